// Round 4
// baseline (504.922 us; speedup 1.0000x reference)
//
#include <hip/hip_runtime.h>

typedef _Float16 f16x8 __attribute__((ext_vector_type(8)));
typedef float    f32x4 __attribute__((ext_vector_type(4)));

#define BHn 64
#define SEQ 2048
#define DIM 64
#define NEGV -1.0e9f
static const size_t ELEMS = (size_t)BHn * SEQ * DIM;   // 8,388,608

// ---------------------------------------------------------------------------
// Fragment layouts (consistent assumed mapping; permutation-immune for A/B):
//  K16 frag elem  ((bh*128+kt)*2+s)*512 + lane*8 + j  <- K[bh][kt*16+(lane&15)][s*32+(lane>>4)*8+j]
//  V16 frag elem  ((bh*64+u)*4+wt)*512 + lane*8 + j   <- V[bh][u*32+(lane>>4)*8+j][wt*16+(lane&15)]
// ---------------------------------------------------------------------------
__global__ __launch_bounds__(256) void convert_kv(
    const float* __restrict__ k, const float* __restrict__ v,
    _Float16* __restrict__ v16, _Float16* __restrict__ k16, int do_k)
{
  int gi = blockIdx.x * 256 + threadIdx.x;
  const int TOTAL_V = BHn * 64 * 4 * 64;   // 1,048,576 groups of 8
  if (gi < TOTAL_V) {
    int lane = gi & 63;
    int wt   = (gi >> 6) & 3;
    int u    = (gi >> 8) & 63;
    int bh   = gi >> 14;
    int d    = wt * 16 + (lane & 15);
    int c0   = u * 32 + ((lane >> 4) << 3);
    const float* src = v + ((size_t)(bh * SEQ + c0)) * DIM + d;
    f16x8 o;
#pragma unroll
    for (int j = 0; j < 8; ++j) o[j] = (_Float16)src[(size_t)j * DIM];
    *(f16x8*)(v16 + (size_t)gi * 8) = o;
  } else if (do_k) {
    int gk = gi - TOTAL_V;
    if (gk < BHn * 128 * 2 * 64) {
      int lane = gk & 63;
      int s    = (gk >> 6) & 1;
      int kt   = (gk >> 7) & 127;
      int bh   = gk >> 14;
      int row  = kt * 16 + (lane & 15);
      int d0   = s * 32 + ((lane >> 4) << 3);
      const float* src = k + ((size_t)(bh * SEQ + row)) * DIM + d0;
      float4 a = *(const float4*)src;
      float4 b = *(const float4*)(src + 4);
      f16x8 o;
      o[0]=(_Float16)a.x; o[1]=(_Float16)a.y; o[2]=(_Float16)a.z; o[3]=(_Float16)a.w;
      o[4]=(_Float16)b.x; o[5]=(_Float16)b.y; o[6]=(_Float16)b.z; o[7]=(_Float16)b.w;
      *(f16x8*)(k16 + (size_t)gk * 8) = o;
    }
  }
}

// ---------------------------------------------------------------------------
// One block = 16 q-rows of one (b,h). 4 waves: wave w owns cols [512w,512w+512)
// for QK^T, then d-interleaved quarter of PV k-chunks. Scores kept in regs.
// ---------------------------------------------------------------------------
template<bool KWS>
__global__ __launch_bounds__(256, 2) void attn_fused(
    const float* __restrict__ q, const float* __restrict__ kf32,
    const int* __restrict__ mask,
    const _Float16* __restrict__ k16, const _Float16* __restrict__ v16,
    float* __restrict__ outO, float* __restrict__ outA)
{
  __shared__ _Float16 P16[16 * SEQ];      // 64 KiB. Early: first 512B = reductions.
  float* redf = (float*)P16;              // [0..63]=rowmax per wave, [64..127]=rowsum

  const int blk  = blockIdx.x;
  const int bh   = blk >> 7;
  const int qt   = blk & 127;
  const int b    = bh >> 4;
  const int tid  = threadIdx.x;
  const int w    = tid >> 6;
  const int lane = tid & 63;
  const int l15  = lane & 15;
  const int g    = lane >> 4;

  // ---- Q A-fragments in regs: row = qt*16+l15, d = s*32 + g*8 + j ----
  const float* qp = q + ((size_t)(bh * SEQ + qt * 16 + l15)) * DIM + g * 8;
  f16x8 qf0, qf1;
  {
    float4 a0 = *(const float4*)(qp);
    float4 a1 = *(const float4*)(qp + 4);
    float4 b0 = *(const float4*)(qp + 32);
    float4 b1 = *(const float4*)(qp + 36);
    qf0[0]=(_Float16)a0.x; qf0[1]=(_Float16)a0.y; qf0[2]=(_Float16)a0.z; qf0[3]=(_Float16)a0.w;
    qf0[4]=(_Float16)a1.x; qf0[5]=(_Float16)a1.y; qf0[6]=(_Float16)a1.z; qf0[7]=(_Float16)a1.w;
    qf1[0]=(_Float16)b0.x; qf1[1]=(_Float16)b0.y; qf1[2]=(_Float16)b0.z; qf1[3]=(_Float16)b0.w;
    qf1[4]=(_Float16)b1.x; qf1[5]=(_Float16)b1.y; qf1[6]=(_Float16)b1.z; qf1[7]=(_Float16)b1.w;
  }

  // ---- QK^T ----
  f32x4 acc[32];
  const f32x4 zz = {0.f, 0.f, 0.f, 0.f};
#pragma unroll
  for (int t = 0; t < 32; ++t) acc[t] = zz;

#pragma unroll
  for (int t = 0; t < 32; ++t) {
    const int kt = (w << 5) + t;
    f16x8 b0, b1;
    if constexpr (KWS) {
      const _Float16* kp = k16 + ((size_t)((bh * 128 + kt) * 2)) * 512 + lane * 8;
      b0 = *(const f16x8*)(kp);
      b1 = *(const f16x8*)(kp + 512);
    } else {
      const float* kp = kf32 + ((size_t)(bh * SEQ + kt * 16 + l15)) * DIM + g * 8;
      float4 x0 = *(const float4*)(kp);
      float4 x1 = *(const float4*)(kp + 4);
      float4 y0 = *(const float4*)(kp + 32);
      float4 y1 = *(const float4*)(kp + 36);
      b0[0]=(_Float16)x0.x; b0[1]=(_Float16)x0.y; b0[2]=(_Float16)x0.z; b0[3]=(_Float16)x0.w;
      b0[4]=(_Float16)x1.x; b0[5]=(_Float16)x1.y; b0[6]=(_Float16)x1.z; b0[7]=(_Float16)x1.w;
      b1[0]=(_Float16)y0.x; b1[1]=(_Float16)y0.y; b1[2]=(_Float16)y0.z; b1[3]=(_Float16)y0.w;
      b1[4]=(_Float16)y1.x; b1[5]=(_Float16)y1.y; b1[6]=(_Float16)y1.z; b1[7]=(_Float16)y1.w;
    }
    acc[t] = __builtin_amdgcn_mfma_f32_16x16x32_f16(qf0, b0, acc[t], 0, 0, 0);
    acc[t] = __builtin_amdgcn_mfma_f32_16x16x32_f16(qf1, b1, acc[t], 0, 0, 0);
  }

  // ---- mask: col per lane = w*512 + t*16 + l15 (same for all 4 acc rows) ----
  const int* mrow = mask + (size_t)b * SEQ;
#pragma unroll
  for (int t = 0; t < 32; ++t) {
    const int c = (w << 9) + (t << 4) + l15;
    if (mrow[c] == 0) { acc[t][0]=NEGV; acc[t][1]=NEGV; acc[t][2]=NEGV; acc[t][3]=NEGV; }
  }

  // ---- row max (rows 4g+i): local over t, then 16-lane shfl, then cross-wave LDS ----
  float mx0=-3.0e38f, mx1=-3.0e38f, mx2=-3.0e38f, mx3=-3.0e38f;
#pragma unroll
  for (int t = 0; t < 32; ++t) {
    mx0 = fmaxf(mx0, acc[t][0]); mx1 = fmaxf(mx1, acc[t][1]);
    mx2 = fmaxf(mx2, acc[t][2]); mx3 = fmaxf(mx3, acc[t][3]);
  }
#pragma unroll
  for (int off = 1; off < 16; off <<= 1) {
    mx0 = fmaxf(mx0, __shfl_xor(mx0, off));
    mx1 = fmaxf(mx1, __shfl_xor(mx1, off));
    mx2 = fmaxf(mx2, __shfl_xor(mx2, off));
    mx3 = fmaxf(mx3, __shfl_xor(mx3, off));
  }
  if (l15 == 0) {
    redf[w*16 + 4*g + 0] = mx0; redf[w*16 + 4*g + 1] = mx1;
    redf[w*16 + 4*g + 2] = mx2; redf[w*16 + 4*g + 3] = mx3;
  }
  __syncthreads();
  const float m0 = fmaxf(fmaxf(redf[ 0+4*g+0], redf[16+4*g+0]), fmaxf(redf[32+4*g+0], redf[48+4*g+0]));
  const float m1 = fmaxf(fmaxf(redf[ 0+4*g+1], redf[16+4*g+1]), fmaxf(redf[32+4*g+1], redf[48+4*g+1]));
  const float m2 = fmaxf(fmaxf(redf[ 0+4*g+2], redf[16+4*g+2]), fmaxf(redf[32+4*g+2], redf[48+4*g+2]));
  const float m3 = fmaxf(fmaxf(redf[ 0+4*g+3], redf[16+4*g+3]), fmaxf(redf[32+4*g+3], redf[48+4*g+3]));

  // ---- exp + row sum ----
  float s0=0.f, s1=0.f, s2=0.f, s3=0.f;
#pragma unroll
  for (int t = 0; t < 32; ++t) {
    float e0 = __expf(acc[t][0] - m0); acc[t][0] = e0; s0 += e0;
    float e1 = __expf(acc[t][1] - m1); acc[t][1] = e1; s1 += e1;
    float e2 = __expf(acc[t][2] - m2); acc[t][2] = e2; s2 += e2;
    float e3 = __expf(acc[t][3] - m3); acc[t][3] = e3; s3 += e3;
  }
#pragma unroll
  for (int off = 1; off < 16; off <<= 1) {
    s0 += __shfl_xor(s0, off); s1 += __shfl_xor(s1, off);
    s2 += __shfl_xor(s2, off); s3 += __shfl_xor(s3, off);
  }
  if (l15 == 0) {
    redf[64 + w*16 + 4*g + 0] = s0; redf[64 + w*16 + 4*g + 1] = s1;
    redf[64 + w*16 + 4*g + 2] = s2; redf[64 + w*16 + 4*g + 3] = s3;
  }
  __syncthreads();
  const float inv0 = 1.0f / (redf[64+ 0+4*g+0] + redf[64+16+4*g+0] + redf[64+32+4*g+0] + redf[64+48+4*g+0]);
  const float inv1 = 1.0f / (redf[64+ 0+4*g+1] + redf[64+16+4*g+1] + redf[64+32+4*g+1] + redf[64+48+4*g+1]);
  const float inv2 = 1.0f / (redf[64+ 0+4*g+2] + redf[64+16+4*g+2] + redf[64+32+4*g+2] + redf[64+48+4*g+2]);
  const float inv3 = 1.0f / (redf[64+ 0+4*g+3] + redf[64+16+4*g+3] + redf[64+32+4*g+3] + redf[64+48+4*g+3]);
  __syncthreads();   // reduction reads done before P16 overwrites redf region

  // ---- store probs as f16 into swizzled LDS [16][2048] (byte ^= (row&7)<<4) ----
#pragma unroll
  for (int t = 0; t < 32; ++t) {
    const int c  = (w << 9) + (t << 4) + l15;
    const int r0 = 4 * g;
    *(_Float16*)((char*)P16 + ((((r0+0)*SEQ + c)*2) ^ (((r0+0)&7)<<4))) = (_Float16)(acc[t][0] * inv0);
    *(_Float16*)((char*)P16 + ((((r0+1)*SEQ + c)*2) ^ (((r0+1)&7)<<4))) = (_Float16)(acc[t][1] * inv1);
    *(_Float16*)((char*)P16 + ((((r0+2)*SEQ + c)*2) ^ (((r0+2)&7)<<4))) = (_Float16)(acc[t][2] * inv2);
    *(_Float16*)((char*)P16 + ((((r0+3)*SEQ + c)*2) ^ (((r0+3)&7)<<4))) = (_Float16)(acc[t][3] * inv3);
  }
  __syncthreads();

  // ---- PV MFMA interleaved with coalesced attn store (1KB/instr full lines) ----
  f32x4 o0 = zz, o1 = zz, o2 = zz, o3 = zz;
  const size_t arowbase = (size_t)(bh * SEQ + qt * 16);
#pragma unroll 2
  for (int uu = 0; uu < 16; ++uu) {
    const int u = uu * 4 + w;
    const f16x8 pa = *(const f16x8*)((const char*)P16 +
                     (((l15*SEQ + u*32 + g*8)*2) ^ ((l15&7)<<4)));
    const _Float16* vp = v16 + ((size_t)((bh*64 + u)*4))*512 + lane*8;
    o0 = __builtin_amdgcn_mfma_f32_16x16x32_f16(pa, *(const f16x8*)(vp       ), o0, 0, 0, 0);
    o1 = __builtin_amdgcn_mfma_f32_16x16x32_f16(pa, *(const f16x8*)(vp +  512), o1, 0, 0, 0);
    o2 = __builtin_amdgcn_mfma_f32_16x16x32_f16(pa, *(const f16x8*)(vp + 1024), o2, 0, 0, 0);
    o3 = __builtin_amdgcn_mfma_f32_16x16x32_f16(pa, *(const f16x8*)(vp + 1536), o3, 0, 0, 0);
#pragma unroll
    for (int h2 = 0; h2 < 2; ++h2) {
      const int flat = (uu*2 + h2)*256 + lane*4;       // wave slab: rows 4w..4w+3
      const int r = 4*w + (flat >> 11);
      const int c = flat & 2047;
      union { uint2 u2; _Float16 hh[4]; } cv;
      cv.u2 = *(const uint2*)((const char*)P16 + (((r*SEQ + c)*2) ^ ((r&7)<<4)));
      float4 ov;
      ov.x = (float)cv.hh[0]; ov.y = (float)cv.hh[1];
      ov.z = (float)cv.hh[2]; ov.w = (float)cv.hh[3];
      *(float4*)(outA + (arowbase + r)*SEQ + c) = ov;
    }
  }
  __syncthreads();

  // ---- cross-wave O reduce via LDS (alias P16: 16 KiB) ----
  float* Opart = (float*)P16;   // [4 waves][16 rows][64 d]
#pragma unroll
  for (int i = 0; i < 4; ++i) {
    Opart[(w*16 + 4*g + i)*64 +  0 + l15] = o0[i];
    Opart[(w*16 + 4*g + i)*64 + 16 + l15] = o1[i];
    Opart[(w*16 + 4*g + i)*64 + 32 + l15] = o2[i];
    Opart[(w*16 + 4*g + i)*64 + 48 + l15] = o3[i];
  }
  __syncthreads();
  {
    const int r = tid >> 4;
    const int d = (tid & 15) << 2;
    float4 p0 = *(const float4*)&Opart[( 0 + r)*64 + d];
    float4 p1 = *(const float4*)&Opart[(16 + r)*64 + d];
    float4 p2 = *(const float4*)&Opart[(32 + r)*64 + d];
    float4 p3 = *(const float4*)&Opart[(48 + r)*64 + d];
    float4 s;
    s.x = p0.x + p1.x + p2.x + p3.x;
    s.y = p0.y + p1.y + p2.y + p3.y;
    s.z = p0.z + p1.z + p2.z + p3.z;
    s.w = p0.w + p1.w + p2.w + p3.w;
    *(float4*)(outO + ((size_t)(bh*SEQ + qt*16 + r))*DIM + d) = s;
  }
}

extern "C" void kernel_launch(void* const* d_in, const int* in_sizes, int n_in,
                              void* d_out, int out_size, void* d_ws, size_t ws_size,
                              hipStream_t stream)
{
  const float* q    = (const float*)d_in[0];
  const float* k    = (const float*)d_in[1];
  const float* v    = (const float*)d_in[2];
  const int*   mask = (const int*)d_in[3];

  float* outO = (float*)d_out;            // [B,H,S,D] fp32
  float* outA = outO + ELEMS;             // [B,H,S,S] fp32

  _Float16* v16 = (_Float16*)d_ws;        // 16.78 MB, fragment-ordered
  _Float16* k16 = v16 + ELEMS;            // +16.78 MB if workspace permits
  const bool kws = (ws_size >= 2 * ELEMS * sizeof(_Float16));

  const int groups = kws ? (2 * 1048576) : 1048576;
  convert_kv<<<groups / 256, 256, 0, stream>>>(k, v, v16, k16, kws ? 1 : 0);

  if (kws)
    attn_fused<true ><<<8192, 256, 0, stream>>>(q, k, mask, k16, v16, outO, outA);
  else
    attn_fused<false><<<8192, 256, 0, stream>>>(q, k, mask, k16, v16, outO, outA);
}